// Round 5
// baseline (230.632 us; speedup 1.0000x reference)
//
#include <hip/hip_runtime.h>
#include <math.h>

namespace {
constexpr int   T_STEPS = 400;
constexpr int   HALF    = 200;           // T/2 — scan covers t = 1..200
constexpr int   NPIX    = 250 * 400;     // 100000
constexpr int   CHUNK   = 32;            // timesteps per load chunk
constexpr int   BLOCK   = 64;            // one wave per block: no LDS, no barriers
constexpr int   NBLK    = (NPIX + BLOCK - 1) / BLOCK;   // 1563
constexpr float U0 = 0.15f;
}

// order-preserving float <-> uint key (for global atomic min/max)
__device__ __forceinline__ unsigned fkey(float f) {
  const unsigned u = __float_as_uint(f);
  return (u & 0x80000000u) ? ~u : (u | 0x80000000u);
}
__device__ __forceinline__ float funkey(unsigned k) {
  const unsigned u = (k & 0x80000000u) ? (k ^ 0x80000000u) : ~k;
  return __uint_as_float(u);
}

// Exact math (R3-verbatim): n recurrence steps with interval d.
__device__ __forceinline__ void apply_segment(float& R, float& u, int d, int n) {
  const float dd = (float)d;
  const float eD = expf(-dd);              // exp(-isi / D), D = 1
  const float eF = expf(-(dd / 10.0f));    // exp(-isi / F), F = 10
  for (int k = 0; k < n; ++k) {
    const float Rn = 1.0f - (1.0f - R * (1.0f - u)) * eD;
    const float un = U0 + (u + 0.15f * (1.0f - u) - U0) * eF;
    R = Rn; u = un;
  }
}

__device__ __forceinline__ void proc_mask(unsigned mask, int t0, int& prev,
                                          float& R, float& u, bool& done) {
  if (done) return;
  while (mask) {
    const int i = __builtin_ctz(mask);
    mask &= mask - 1u;
    const int t = t0 + i;
    if (prev >= 0) {
      const int d = t - prev;
      // t <= HALF: segment (prev, t], endpoint updates only when isi==1
      // t >  HALF: segment clipped to (prev, HALF]
      const int n = (t <= HALF) ? ((d == 1) ? 1 : (d - 1)) : (HALF - prev);
      apply_segment(R, u, d, n);
    }
    prev = t;
    if (t >= HALF) { done = true; return; }
  }
}

// Single fused kernel: recurrence -> keyed global atomic min/max ->
// spin barrier on device-scope counter -> in-register normalize -> store.
// Co-residency by construction: __launch_bounds__(64,2) => 8 blocks/CU
// capacity (2048 blocks) >= NBLK=1563, so all blocks become resident and
// the counter reaches NBLK regardless of dispatch order.
__global__ __launch_bounds__(BLOCK, 2) void stp_fused(
    const float* __restrict__ spikes, float* __restrict__ img,
    unsigned* __restrict__ mm, unsigned* __restrict__ sync_ctr) {
  const int  p      = blockIdx.x * BLOCK + threadIdx.x;
  const bool active = (p < NPIX);
  const float* __restrict__ sp = spikes + (active ? p : (NPIX - 1));

  bool  done = !active;
  int   prev = -1;
  float R = 1.0f, u = U0;

  auto loadc = [&](float (&buf)[CHUNK], int c) {
#pragma unroll
    for (int i = 0; i < CHUNK; ++i) {
      const unsigned idx = (unsigned)(c * CHUNK + i) * (unsigned)NPIX;
      buf[i] = sp[idx];
    }
  };
  auto maskof = [&](const float (&buf)[CHUNK]) -> unsigned {
    unsigned m = 0u;
#pragma unroll
    for (int i = 0; i < CHUNK; ++i) m |= (buf[i] > 0.0f) ? (1u << i) : 0u;
    return m;
  };

  // Software-pipelined double buffer; chunks 0..6 cover t in [0,224).
  float va[CHUNK], vb[CHUNK];
  loadc(va, 0);
  loadc(vb, 1);
  unsigned m;
  m = maskof(va); loadc(va, 2); proc_mask(m, 0 * CHUNK, prev, R, u, done);
  m = maskof(vb); loadc(vb, 3); proc_mask(m, 1 * CHUNK, prev, R, u, done);
  m = maskof(va); loadc(va, 4); proc_mask(m, 2 * CHUNK, prev, R, u, done);
  m = maskof(vb); loadc(vb, 5); proc_mask(m, 3 * CHUNK, prev, R, u, done);
  m = maskof(va); loadc(va, 6); proc_mask(m, 4 * CHUNK, prev, R, u, done);
  m = maskof(vb);               proc_mask(m, 5 * CHUNK, prev, R, u, done);
  m = maskof(va);               proc_mask(m, 6 * CHUNK, prev, R, u, done);

  // Rare tail (P ~ 64 * 2^-24 per wave); exact fallback on raw spikes.
  for (int c = 7; c <= (T_STEPS - 1) / CHUNK; ++c) {
    if (__all(done ? 1 : 0)) break;
    unsigned mt = 0u;
#pragma unroll
    for (int i = 0; i < CHUNK; ++i) {
      const int t = c * CHUNK + i;
      float v = 0.0f;
      if (t < T_STEPS) v = sp[(unsigned)t * (unsigned)NPIX];
      mt |= (v > 0.0f) ? (1u << i) : 0u;
    }
    proc_mask(mt, c * CHUNK, prev, R, u, done);
  }

  float val = 0.0f;
  if (active) {
    const float lu = logf((u - U0) / (10.0f - U0 + u * 0.85f));
    const float lR = logf((1.0f - R) / (1.0f - R * (1.0f - u)));
    val = (-1.0f / (10.0f * lu)) + (-1.0f / lR);
  }

  // wave min/max -> one keyed atomic pair per block, then release the counter
  float vmin = active ? val : INFINITY;
  float vmax = active ? val : -INFINITY;
#pragma unroll
  for (int off = 32; off > 0; off >>= 1) {
    vmin = fminf(vmin, __shfl_down(vmin, off, 64));
    vmax = fmaxf(vmax, __shfl_down(vmax, off, 64));
  }
  if (threadIdx.x == 0) {
    atomicMin(&mm[0], fkey(vmin));     // device-scope by default
    atomicMax(&mm[1], fkey(vmax));
    __hip_atomic_fetch_add(&sync_ctr[0], 1u, __ATOMIC_RELEASE,
                           __HIP_MEMORY_SCOPE_AGENT);
  }

  // spin until all blocks contributed (all resident by launch_bounds math)
  while (__hip_atomic_load(&sync_ctr[0], __ATOMIC_ACQUIRE,
                           __HIP_MEMORY_SCOPE_AGENT) < (unsigned)NBLK) {
    __builtin_amdgcn_s_sleep(8);
  }

  const float mn = funkey(__hip_atomic_load(&mm[0], __ATOMIC_RELAXED,
                                            __HIP_MEMORY_SCOPE_AGENT));
  const float mx = funkey(__hip_atomic_load(&mm[1], __ATOMIC_RELAXED,
                                            __HIP_MEMORY_SCOPE_AGENT));
  if (active) {
    img[p] = (mx != mn) ? (val - mn) / (mx - mn) : val;
  }
}

extern "C" void kernel_launch(void* const* d_in, const int* in_sizes, int n_in,
                              void* d_out, int out_size, void* d_ws, size_t ws_size,
                              hipStream_t stream) {
  const float* spikes = (const float*)d_in[0];
  float*    out = (float*)d_out;
  unsigned* mm  = (unsigned*)d_ws;        // [0]=min key, [1]=max key, [2]=sync
  unsigned* syn = (unsigned*)d_ws + 2;

  // re-init 12-byte sync area every call (deterministic across replays)
  hipMemsetAsync(mm, 0xFF, 4, stream);          // mm[0] = 0xFFFFFFFF (min key id)
  hipMemsetAsync(mm + 1, 0x00, 8, stream);      // mm[1] = 0, sync = 0

  hipLaunchKernelGGL(stp_fused, dim3(NBLK), dim3(BLOCK), 0, stream,
                     spikes, out, mm, syn);
}

// Round 6
// 113.654 us; speedup vs baseline: 2.0292x; 2.0292x over previous
//
#include <hip/hip_runtime.h>
#include <math.h>

namespace {
constexpr int   T_STEPS = 400;
constexpr int   HALF    = 200;            // T/2 — scan covers t = 1..200
constexpr int   NPIX    = 250 * 400;      // 100000
constexpr int   NWORDS  = 7;              // packed words cover t in [0, 224)
constexpr int   PACK_BLOCK = 256;
constexpr int   PXQ        = NPIX / 4;    // 25000 pixel-quads (float4 lanes)
constexpr int   PACK_PXBLK = (PXQ + PACK_BLOCK - 1) / PACK_BLOCK;   // 98
constexpr int   REC_BLOCK  = 64;          // one wave: no LDS, no barriers
constexpr int   REC_NBLK   = (NPIX + REC_BLOCK - 1) / REC_BLOCK;    // 1563
constexpr int   NORM_BLOCK = 256;
constexpr int   NORM_NBLK  = (NPIX + NORM_BLOCK - 1) / NORM_BLOCK;
constexpr float U0 = 0.15f;
}

// order-preserving float <-> uint key (for global atomic min/max)
__device__ __forceinline__ unsigned fkey(float f) {
  const unsigned u = __float_as_uint(f);
  return (u & 0x80000000u) ? ~u : (u | 0x80000000u);
}
__device__ __forceinline__ float funkey(unsigned k) {
  const unsigned u = (k & 0x80000000u) ? (k ^ 0x80000000u) : ~k;
  return __uint_as_float(u);
}

// ---------------- Pass 1: stream spikes -> packed bitmasks ----------------
// Grid (98, 7): block (x) covers 1024 pixels, (y) covers one 32-timestep word.
// Each thread: 32 INDEPENDENT float4 loads (launch_bounds(256,2) -> 128 VGPR
// cap keeps ~24 in flight), 32 cmp+or, one uint4 store. 2744 waves total.
__global__ __launch_bounds__(PACK_BLOCK, 2) void pack_spikes(
    const float* __restrict__ spikes, unsigned* __restrict__ packed) {
  const int q = blockIdx.x * PACK_BLOCK + threadIdx.x;
  if (q >= PXQ) return;
  const int w  = blockIdx.y;
  const int px = q * 4;
  const float4* __restrict__ base =
      reinterpret_cast<const float4*>(spikes + (size_t)(w * 32) * NPIX) + q;
  unsigned b0 = 0u, b1 = 0u, b2 = 0u, b3 = 0u;
#pragma unroll
  for (int t = 0; t < 32; ++t) {
    const float4 v = base[(size_t)t * (NPIX / 4)];
    const unsigned bit = 1u << t;
    b0 |= (v.x > 0.0f) ? bit : 0u;
    b1 |= (v.y > 0.0f) ? bit : 0u;
    b2 |= (v.z > 0.0f) ? bit : 0u;
    b3 |= (v.w > 0.0f) ? bit : 0u;
  }
  *reinterpret_cast<uint4*>(packed + (size_t)w * NPIX + px) =
      make_uint4(b0, b1, b2, b3);
}

// ---------------- Pass 2: serial recurrence over packed bits ----------------
// Exact math (R3-verbatim): n recurrence steps with interval d.
__device__ __forceinline__ void apply_segment(float& R, float& u, int d, int n) {
  const float dd = (float)d;
  const float eD = expf(-dd);              // exp(-isi / D), D = 1
  const float eF = expf(-(dd / 10.0f));    // exp(-isi / F), F = 10
  for (int k = 0; k < n; ++k) {
    const float Rn = 1.0f - (1.0f - R * (1.0f - u)) * eD;
    const float un = U0 + (u + 0.15f * (1.0f - u) - U0) * eF;
    R = Rn; u = un;
  }
}

__device__ __forceinline__ void proc_mask(unsigned mask, int t0, int& prev,
                                          float& R, float& u, bool& done) {
  if (done) return;
  while (mask) {
    const int i = __builtin_ctz(mask);
    mask &= mask - 1u;
    const int t = t0 + i;
    if (prev >= 0) {
      const int d = t - prev;
      // t <= HALF: segment (prev, t], endpoint updates only when isi==1
      // t >  HALF: segment clipped to (prev, HALF]
      const int n = (t <= HALF) ? ((d == 1) ? 1 : (d - 1)) : (HALF - prev);
      apply_segment(R, u, d, n);
    }
    prev = t;
    if (t >= HALF) { done = true; return; }
  }
}

__global__ __launch_bounds__(REC_BLOCK) void stp_recur(
    const unsigned* __restrict__ packed, const float* __restrict__ spikes,
    float* __restrict__ img, unsigned* __restrict__ mm) {
  const int  p      = blockIdx.x * REC_BLOCK + threadIdx.x;
  const bool active = (p < NPIX);
  const int  pc     = active ? p : (NPIX - 1);

  bool  done = !active;
  int   prev = -1;
  float R = 1.0f, u = U0;

  unsigned mw[NWORDS];
#pragma unroll
  for (int w = 0; w < NWORDS; ++w) mw[w] = packed[(size_t)w * NPIX + pc];
#pragma unroll
  for (int w = 0; w < NWORDS; ++w) proc_mask(mw[w], w * 32, prev, R, u, done);

  // Rare tail: no spike in [200,224) for some lane (P ~ 6e-8/pixel).
  // Exact fallback on raw spikes rows t >= 224.
  if (__any(done ? 0 : 1)) {
    const float* spt = spikes + pc;
    for (int t = NWORDS * 32; t < T_STEPS; ++t) {
      if (__all(done ? 1 : 0)) break;
      const float v = spt[(size_t)t * NPIX];
      if (!done && v > 0.0f) {
        if (prev >= 0) apply_segment(R, u, t - prev, HALF - prev);
        prev = t;
        done = true;            // t >= 224 > HALF
      }
    }
  }
  // Lanes never done: trailing steps have isi = inf -> no update. Exact.

  float val = 0.0f;
  if (active) {
    const float lu = logf((u - U0) / (10.0f - U0 + u * 0.85f));
    const float lR = logf((1.0f - R) / (1.0f - R * (1.0f - u)));
    val = (-1.0f / (10.0f * lu)) + (-1.0f / lR);
    img[p] = val;
  }

  // wave min/max -> one keyed atomic pair per block (no polling anywhere)
  float vmin = active ? val : INFINITY;
  float vmax = active ? val : -INFINITY;
#pragma unroll
  for (int off = 32; off > 0; off >>= 1) {
    vmin = fminf(vmin, __shfl_down(vmin, off, 64));
    vmax = fmaxf(vmax, __shfl_down(vmax, off, 64));
  }
  if (threadIdx.x == 0) {
    atomicMin(&mm[0], fkey(vmin));
    atomicMax(&mm[1], fkey(vmax));
  }
}

// ---------------- Pass 3: normalize ----------------
__global__ __launch_bounds__(NORM_BLOCK) void normalize_k(
    float* __restrict__ img, const unsigned* __restrict__ mm) {
  const int p = blockIdx.x * NORM_BLOCK + threadIdx.x;
  if (p < NPIX) {
    const float mn = funkey(mm[0]);
    const float mx = funkey(mm[1]);
    const float v  = img[p];
    img[p] = (mx != mn) ? (v - mn) / (mx - mn) : v;
  }
}

extern "C" void kernel_launch(void* const* d_in, const int* in_sizes, int n_in,
                              void* d_out, int out_size, void* d_ws, size_t ws_size,
                              hipStream_t stream) {
  const float* spikes = (const float*)d_in[0];
  float*    out    = (float*)d_out;
  unsigned* mm     = (unsigned*)d_ws;                 // [0]=min key, [1]=max key
  unsigned* packed = (unsigned*)d_ws + 64;            // 7 * NPIX words (2.8 MB)

  // keyed min/max identity init (8 bytes, deterministic per replay)
  hipMemsetAsync(mm, 0xFF, 4, stream);                // min slot = 0xFFFFFFFF
  hipMemsetAsync(mm + 1, 0x00, 4, stream);            // max slot = 0

  hipLaunchKernelGGL(pack_spikes, dim3(PACK_PXBLK, NWORDS), dim3(PACK_BLOCK),
                     0, stream, spikes, packed);
  hipLaunchKernelGGL(stp_recur, dim3(REC_NBLK), dim3(REC_BLOCK), 0, stream,
                     packed, spikes, out, mm);
  hipLaunchKernelGGL(normalize_k, dim3(NORM_NBLK), dim3(NORM_BLOCK), 0, stream,
                     out, mm);
}